// Round 3
// baseline (69.070 us; speedup 1.0000x reference)
//
#include <hip/hip_runtime.h>

// HSTU block preprocessor: jagged concat of [ctx1 | ctx2 | interleave(item, action)]
// per sample, plus merged lengths (fused: block 0 writes lengths).
// Pure memory-bound row gather/copy.
//
// One wave (64 lanes) copies CHUNK=8 consecutive output rows (16 KiB):
// binary-search the sample once, advance monotonically, precompute 8 src
// pointers, then batch 16 float4 loads -> 16 nontemporal float4 stores.

#define HSTU_D 512
#define F4_PER_ROW (HSTU_D / 4)   // 128
#define MAX_B 1024                // LDS sized for up to 1024 samples (B=128 here)
#define CHUNK 8                   // rows per wave
#define WAVES_PER_BLOCK 4

typedef float f32x4 __attribute__((ext_vector_type(4)));

__global__ __launch_bounds__(256) void hstu_concat_kernel(
    const f32x4* __restrict__ item, const f32x4* __restrict__ action,
    const f32x4* __restrict__ ctx1, const f32x4* __restrict__ ctx2,
    const int* __restrict__ it_off, const int* __restrict__ c1_off,
    const int* __restrict__ c2_off,
    f32x4* __restrict__ out, float* __restrict__ out_len,
    int B, int total_rows) {
    __shared__ int s_it[MAX_B + 1], s_c1[MAX_B + 1], s_c2[MAX_B + 1], s_base[MAX_B + 1];

    for (int i = threadIdx.x; i <= B; i += blockDim.x) {
        int a  = it_off[i];
        int b1 = c1_off[i];
        int b2 = c2_off[i];
        s_it[i]   = a;
        s_c1[i]   = b1;
        s_c2[i]   = b2;
        s_base[i] = b1 + b2 + 2 * a;   // output row offset of sample i
    }
    __syncthreads();

    // Fused lengths write: block 0 only (B values).
    if (blockIdx.x == 0 && (int)threadIdx.x < B) {
        int i = threadIdx.x;
        int len = (s_c1[i + 1] - s_c1[i]) + (s_c2[i + 1] - s_c2[i])
                + 2 * (s_it[i + 1] - s_it[i]);
        out_len[i] = (float)len;
    }

    const int wave  = threadIdx.x >> 6;
    const int lane  = threadIdx.x & 63;
    const int gwave = blockIdx.x * WAVES_PER_BLOCK + wave;
    const int row0  = gwave * CHUNK;
    if (row0 >= total_rows) return;
    const int nrows = min(CHUNK, total_rows - row0);

    // Largest b with s_base[b] <= row0 (wave-uniform binary search).
    int lo = 0, hi = B;
    while (hi - lo > 1) {
        int mid = (lo + hi) >> 1;
        if (s_base[mid] <= row0) lo = mid; else hi = mid;
    }
    int b = lo;

    // Precompute source pointers for the chunk (b advances monotonically;
    // a chunk of 8 rows crosses at most one sample boundary here).
    const f32x4* srcs[CHUNK];
#pragma unroll
    for (int i = 0; i < CHUNK; ++i) {
        srcs[i] = item;  // safe default for inactive slots
        if (i < nrows) {
            int row = row0 + i;
            while (row >= s_base[b + 1]) ++b;
            int local = row - s_base[b];
            int l1 = s_c1[b + 1] - s_c1[b];
            int l2 = s_c2[b + 1] - s_c2[b];
            if (local < l1) {
                srcs[i] = ctx1 + (size_t)(s_c1[b] + local) * F4_PER_ROW;
            } else if (local < l1 + l2) {
                srcs[i] = ctx2 + (size_t)(s_c2[b] + (local - l1)) * F4_PER_ROW;
            } else {
                int t = local - l1 - l2;       // position within interleaved block
                int r = s_it[b] + (t >> 1);    // source item/action row
                srcs[i] = ((t & 1) ? action : item) + (size_t)r * F4_PER_ROW;
            }
        }
    }

    // Batch all loads (16 in flight), then all nontemporal stores.
    f32x4 v0[CHUNK], v1[CHUNK];
#pragma unroll
    for (int i = 0; i < CHUNK; ++i) {
        if (i < nrows) {
            v0[i] = srcs[i][lane];
            v1[i] = srcs[i][lane + 64];
        }
    }
    f32x4* __restrict__ dst = out + (size_t)row0 * F4_PER_ROW;
#pragma unroll
    for (int i = 0; i < CHUNK; ++i) {
        if (i < nrows) {
            __builtin_nontemporal_store(v0[i], dst + (size_t)i * F4_PER_ROW + lane);
            __builtin_nontemporal_store(v1[i], dst + (size_t)i * F4_PER_ROW + lane + 64);
        }
    }
}

extern "C" void kernel_launch(void* const* d_in, const int* in_sizes, int n_in,
                              void* d_out, int out_size, void* d_ws, size_t ws_size,
                              hipStream_t stream) {
    const f32x4* item   = (const f32x4*)d_in[0];
    const f32x4* action = (const f32x4*)d_in[1];
    const f32x4* ctx1   = (const f32x4*)d_in[2];
    const f32x4* ctx2   = (const f32x4*)d_in[3];
    const int* it_off   = (const int*)d_in[4];
    const int* c1_off   = (const int*)d_in[5];
    const int* c2_off   = (const int*)d_in[6];

    const int B = in_sizes[4] - 1;
    const long long total_elems = (long long)in_sizes[0] + in_sizes[1]
                                + in_sizes[2] + in_sizes[3];
    const int total_rows = (int)(total_elems / HSTU_D);

    float* out     = (float*)d_out;
    float* out_len = out + (size_t)total_rows * HSTU_D;  // lengths tail

    const int rows_per_block = CHUNK * WAVES_PER_BLOCK;  // 32
    const int grid = (total_rows + rows_per_block - 1) / rows_per_block;
    hstu_concat_kernel<<<grid, 256, 0, stream>>>(
        item, action, ctx1, ctx2, it_off, c1_off, c2_off,
        (f32x4*)out, out_len, B, total_rows);
}

// Round 4
// 36.014 us; speedup vs baseline: 1.9179x; 1.9179x over previous
//
#include <hip/hip_runtime.h>

// HSTU block preprocessor: jagged concat of [ctx1 | ctx2 | interleave(item, action)]
// per sample, plus merged lengths (fused: block 0 writes lengths).
// Pure memory-bound row gather/copy.
//
// One wave (64 lanes) copies CHUNK=2 consecutive output rows (4 KiB):
// 4 float4 loads in flight -> 4 nontemporal float4 stores. Keeps VGPR low
// (round-3 post-mortem: CHUNK=8 -> 204 VGPR -> 9% occupancy -> 2x regression).

#define HSTU_D 512
#define F4_PER_ROW (HSTU_D / 4)   // 128
#define MAX_B 1024                // LDS sized for up to 1024 samples (B=128 here)
#define CHUNK 2                   // rows per wave
#define WAVES_PER_BLOCK 4

typedef float f32x4 __attribute__((ext_vector_type(4)));

__global__ __launch_bounds__(256) void hstu_concat_kernel(
    const f32x4* __restrict__ item, const f32x4* __restrict__ action,
    const f32x4* __restrict__ ctx1, const f32x4* __restrict__ ctx2,
    const int* __restrict__ it_off, const int* __restrict__ c1_off,
    const int* __restrict__ c2_off,
    f32x4* __restrict__ out, float* __restrict__ out_len,
    int B, int total_rows) {
    __shared__ int s_it[MAX_B + 1], s_c1[MAX_B + 1], s_c2[MAX_B + 1], s_base[MAX_B + 1];

    for (int i = threadIdx.x; i <= B; i += blockDim.x) {
        int a  = it_off[i];
        int b1 = c1_off[i];
        int b2 = c2_off[i];
        s_it[i]   = a;
        s_c1[i]   = b1;
        s_c2[i]   = b2;
        s_base[i] = b1 + b2 + 2 * a;   // output row offset of sample i
    }
    __syncthreads();

    // Fused lengths write: block 0 only (B values).
    if (blockIdx.x == 0 && (int)threadIdx.x < B) {
        int i = threadIdx.x;
        int len = (s_c1[i + 1] - s_c1[i]) + (s_c2[i + 1] - s_c2[i])
                + 2 * (s_it[i + 1] - s_it[i]);
        out_len[i] = (float)len;
    }

    const int wave  = threadIdx.x >> 6;
    const int lane  = threadIdx.x & 63;
    const int gwave = blockIdx.x * WAVES_PER_BLOCK + wave;
    const int row0  = gwave * CHUNK;
    if (row0 >= total_rows) return;

    // Largest b with s_base[b] <= row0 (wave-uniform binary search).
    int lo = 0, hi = B;
    while (hi - lo > 1) {
        int mid = (lo + hi) >> 1;
        if (s_base[mid] <= row0) lo = mid; else hi = mid;
    }
    int b = lo;

    // Source pointer for one output row (advances b monotonically).
    auto src_for = [&](int row) -> const f32x4* {
        while (row >= s_base[b + 1]) ++b;
        int local = row - s_base[b];
        int l1 = s_c1[b + 1] - s_c1[b];
        int l2 = s_c2[b + 1] - s_c2[b];
        if (local < l1)
            return ctx1 + (size_t)(s_c1[b] + local) * F4_PER_ROW;
        if (local < l1 + l2)
            return ctx2 + (size_t)(s_c2[b] + (local - l1)) * F4_PER_ROW;
        int t = local - l1 - l2;           // position within interleaved block
        int r = s_it[b] + (t >> 1);        // source item/action row
        return ((t & 1) ? action : item) + (size_t)r * F4_PER_ROW;
    };

    const f32x4* sA = src_for(row0);
    const bool has2 = (row0 + 1) < total_rows;
    const f32x4* sB = has2 ? src_for(row0 + 1) : sA;

    // 4 loads in flight, then 4 nontemporal stores.
    f32x4 a0 = sA[lane];
    f32x4 a1 = sA[lane + 64];
    f32x4 b0 = sB[lane];
    f32x4 b1 = sB[lane + 64];

    f32x4* __restrict__ dst = out + (size_t)row0 * F4_PER_ROW;
    __builtin_nontemporal_store(a0, dst + lane);
    __builtin_nontemporal_store(a1, dst + lane + 64);
    if (has2) {
        __builtin_nontemporal_store(b0, dst + F4_PER_ROW + lane);
        __builtin_nontemporal_store(b1, dst + F4_PER_ROW + lane + 64);
    }
}

extern "C" void kernel_launch(void* const* d_in, const int* in_sizes, int n_in,
                              void* d_out, int out_size, void* d_ws, size_t ws_size,
                              hipStream_t stream) {
    const f32x4* item   = (const f32x4*)d_in[0];
    const f32x4* action = (const f32x4*)d_in[1];
    const f32x4* ctx1   = (const f32x4*)d_in[2];
    const f32x4* ctx2   = (const f32x4*)d_in[3];
    const int* it_off   = (const int*)d_in[4];
    const int* c1_off   = (const int*)d_in[5];
    const int* c2_off   = (const int*)d_in[6];

    const int B = in_sizes[4] - 1;
    const long long total_elems = (long long)in_sizes[0] + in_sizes[1]
                                + in_sizes[2] + in_sizes[3];
    const int total_rows = (int)(total_elems / HSTU_D);

    float* out     = (float*)d_out;
    float* out_len = out + (size_t)total_rows * HSTU_D;  // lengths tail

    const int rows_per_block = CHUNK * WAVES_PER_BLOCK;  // 8
    const int grid = (total_rows + rows_per_block - 1) / rows_per_block;
    hstu_concat_kernel<<<grid, 256, 0, stream>>>(
        item, action, ctx1, ctx2, it_off, c1_off, c2_off,
        (f32x4*)out, out_len, B, total_rows);
}

// Round 5
// 35.370 us; speedup vs baseline: 1.9528x; 1.0182x over previous
//
#include <hip/hip_runtime.h>

// HSTU block preprocessor: jagged concat of [ctx1 | ctx2 | interleave(item, action)]
// per sample, plus merged lengths (fused: block 0 writes lengths).
// Pure memory-bound row gather/copy. One wave (64 lanes) copies one 2 KiB row.
//
// Round-3 post-mortem: CHUNK=8 -> 204 VGPR -> 9% occupancy -> 2x regression.
// Round-4 post-mortem: CHUNK=2 neutral. This round: CHUNK=1 + shrink LDS
// (MAX_B 1024 -> 256: 16.9 KB -> 4.2 KB/block) to lift the LDS occupancy cap.

#define HSTU_D 512
#define F4_PER_ROW (HSTU_D / 4)   // 128
#define MAX_B 256                 // B=128 in this problem; 4 arrays x 257 x 4B = 4.1 KB
#define WAVES_PER_BLOCK 4

typedef float f32x4 __attribute__((ext_vector_type(4)));

__global__ __launch_bounds__(256) void hstu_concat_kernel(
    const f32x4* __restrict__ item, const f32x4* __restrict__ action,
    const f32x4* __restrict__ ctx1, const f32x4* __restrict__ ctx2,
    const int* __restrict__ it_off, const int* __restrict__ c1_off,
    const int* __restrict__ c2_off,
    f32x4* __restrict__ out, float* __restrict__ out_len,
    int B, int total_rows) {
    __shared__ int s_it[MAX_B + 1], s_c1[MAX_B + 1], s_c2[MAX_B + 1], s_base[MAX_B + 1];

    for (int i = threadIdx.x; i <= B; i += blockDim.x) {
        int a  = it_off[i];
        int b1 = c1_off[i];
        int b2 = c2_off[i];
        s_it[i]   = a;
        s_c1[i]   = b1;
        s_c2[i]   = b2;
        s_base[i] = b1 + b2 + 2 * a;   // output row offset of sample i
    }
    __syncthreads();

    // Fused lengths write: block 0 only (B values).
    if (blockIdx.x == 0 && (int)threadIdx.x < B) {
        int i = threadIdx.x;
        int len = (s_c1[i + 1] - s_c1[i]) + (s_c2[i + 1] - s_c2[i])
                + 2 * (s_it[i + 1] - s_it[i]);
        out_len[i] = (float)len;
    }

    const int wave = threadIdx.x >> 6;      // 0..3
    const int lane = threadIdx.x & 63;
    const int row  = blockIdx.x * WAVES_PER_BLOCK + wave;
    if (row >= total_rows) return;

    // Largest b with s_base[b] <= row. Invariant: s_base[lo] <= row < s_base[hi].
    int lo = 0, hi = B;
    while (hi - lo > 1) {
        int mid = (lo + hi) >> 1;
        if (s_base[mid] <= row) lo = mid; else hi = mid;
    }
    const int b     = lo;
    const int local = row - s_base[b];
    const int l1    = s_c1[b + 1] - s_c1[b];
    const int l2    = s_c2[b + 1] - s_c2[b];

    const f32x4* __restrict__ src;
    if (local < l1) {
        src = ctx1 + (size_t)(s_c1[b] + local) * F4_PER_ROW;
    } else if (local < l1 + l2) {
        src = ctx2 + (size_t)(s_c2[b] + (local - l1)) * F4_PER_ROW;
    } else {
        int t = local - l1 - l2;               // position within interleaved block
        int r = s_it[b] + (t >> 1);            // source item/action row
        src = ((t & 1) ? action : item) + (size_t)r * F4_PER_ROW;
    }

    f32x4* __restrict__ dst = out + (size_t)row * F4_PER_ROW;
    f32x4 v0 = src[lane];
    f32x4 v1 = src[lane + 64];
    __builtin_nontemporal_store(v0, dst + lane);
    __builtin_nontemporal_store(v1, dst + lane + 64);
}

extern "C" void kernel_launch(void* const* d_in, const int* in_sizes, int n_in,
                              void* d_out, int out_size, void* d_ws, size_t ws_size,
                              hipStream_t stream) {
    const f32x4* item   = (const f32x4*)d_in[0];
    const f32x4* action = (const f32x4*)d_in[1];
    const f32x4* ctx1   = (const f32x4*)d_in[2];
    const f32x4* ctx2   = (const f32x4*)d_in[3];
    const int* it_off   = (const int*)d_in[4];
    const int* c1_off   = (const int*)d_in[5];
    const int* c2_off   = (const int*)d_in[6];

    const int B = in_sizes[4] - 1;
    const long long total_elems = (long long)in_sizes[0] + in_sizes[1]
                                + in_sizes[2] + in_sizes[3];
    const int total_rows = (int)(total_elems / HSTU_D);

    float* out     = (float*)d_out;
    float* out_len = out + (size_t)total_rows * HSTU_D;  // lengths tail

    const int grid = (total_rows + WAVES_PER_BLOCK - 1) / WAVES_PER_BLOCK;
    hstu_concat_kernel<<<grid, 256, 0, stream>>>(
        item, action, ctx1, ctx2, it_off, c1_off, c2_off,
        (f32x4*)out, out_len, B, total_rows);
}